// Round 10
// baseline (216.586 us; speedup 1.0000x reference)
//
#include <hip/hip_runtime.h>
#include <hip/hip_bf16.h>

#define BB 16
#define NN 1024
#define CS 256
#define CX 64
#define CC 320
#define PH 64
#define GH 128
#define ELLW 64
#define MTILE 128   // edges per block (8 waves x 1 mtile)

typedef __hip_bfloat16 bf16;
typedef __attribute__((ext_vector_type(8))) __bf16 bfrag;   // 8 bf16 = 4 VGPRs
typedef __attribute__((ext_vector_type(4))) float v4f;

// ---------------- prep: pack W1 + gc1_w (hi/lo split) into B-frag order --
// frag[ks][nt][lane][j] = w[k][n], k=ks*32+(lane>>4)*8+j, n=nt*16+(lane&15)
__global__ __launch_bounds__(256) void k_prep(
    const float* __restrict__ w1, const float* __restrict__ gc1w,
    __bf16* __restrict__ whi, __bf16* __restrict__ wlo,
    __bf16* __restrict__ gwhi, __bf16* __restrict__ gwlo,
    int* __restrict__ cnt, float* __restrict__ Ssum, float* __restrict__ S2sum)
{
    int idx = blockIdx.x * 256 + threadIdx.x;
    if (idx < 10 * 4 * 64 * 8) {          // W1: PH=64 -> 4 ntiles
        int j    = idx & 7;
        int lane = (idx >> 3) & 63;
        int nt   = (idx >> 9) & 3;
        int ks   = idx >> 11;
        int k = ks * 32 + (lane >> 4) * 8 + j;
        int n = nt * 16 + (lane & 15);
        float w = w1[k * PH + n];
        __bf16 h = (__bf16)w;
        whi[idx] = h;
        wlo[idx] = (__bf16)(w - (float)h);
    }
    if (idx < 10 * 8 * 64 * 8) {          // gc1_w: GH=128 -> 8 ntiles
        int j    = idx & 7;
        int lane = (idx >> 3) & 63;
        int nt   = (idx >> 9) & 7;
        int ks   = idx >> 12;
        int k = ks * 32 + (lane >> 4) * 8 + j;
        int n = nt * 16 + (lane & 15);
        float w = gc1w[k * GH + n];
        __bf16 h = (__bf16)w;
        gwhi[idx] = h;
        gwlo[idx] = (__bf16)(w - (float)h);
    }
    if (idx < BB * NN) cnt[idx] = 0;
    if (idx < BB * PH) { Ssum[idx] = 0.f; S2sum[idx] = 0.f; }
}

// ---------------- transpose: [B,C,N] -> featT [B,N,C] f32 ----------------
__global__ __launch_bounds__(256) void k_transpose(
    const float* __restrict__ search, const float* __restrict__ xcorr,
    float* __restrict__ featT)
{
    __shared__ float tile[32][33];
    int blk = blockIdx.x;
    int b   = blk % BB;
    int rem = blk / BB;       // 0..319
    int ct  = rem >> 5;       // 10 channel tiles
    int ntl = rem & 31;       // 32 node tiles
    int tid = threadIdx.x;
    int cl = tid >> 5, nl = tid & 31;
    const float* sb = search + (size_t)b * CS * NN;
    const float* xb = xcorr + (size_t)b * CX * NN;
    #pragma unroll
    for (int f = 0; f < 4; ++f) {
        int c = ct * 32 + cl + f * 8;
        int n = ntl * 32 + nl;
        float v = (c < CS) ? sb[(size_t)c * NN + n] : xb[(size_t)(c - CS) * NN + n];
        tile[cl + f * 8][nl] = v;
    }
    __syncthreads();
    #pragma unroll
    for (int f = 0; f < 4; ++f) {
        int nr = cl + f * 8;
        int cc = nl;
        featT[((size_t)b * NN + ntl * 32 + nr) * CC + ct * 32 + cc] = tile[cc][nr];
    }
}

// ------ stage 1: h = |f_i - f_j| @ W1 (split-bf16 MFMA) -> f32 [B,E,64]
//   512 threads / 8 waves, 1 mtile per wave -> prefetch state fits VGPRs.
//   80 KB whi||wlo staged once per block in LDS (amortized over 8 waves);
//   BN-stat LDS aliased into Wsh after the K-loop. 3-deep A prefetch.
__global__ __launch_bounds__(512, 4) void k_edge_gemm(
    const float* __restrict__ featT, const int* __restrict__ pairs,
    const uint4* __restrict__ wglob,   // whi||wlo contiguous, 81920 B
    const float* __restrict__ b1, float* __restrict__ hstore,
    float* __restrict__ Ssum, float* __restrict__ S2sum, int E)
{
    __shared__ ushort Wsh[40960];      // 80 KB: [0:20480) hi, [20480:40960) lo
    float* sS  = (float*)Wsh;          // valid only AFTER post-K-loop barrier
    float* sS2 = ((float*)Wsh) + PH;

    int t = threadIdx.x;
    {   // cooperative W load: 5120 uint4, 10 per thread
        uint4* dst = (uint4*)Wsh;
        #pragma unroll
        for (int k = 0; k < 10; ++k)
            dst[t + k * 512] = wglob[t + k * 512];
    }

    int b  = blockIdx.x % BB;
    int e0 = (blockIdx.x / BB) * MTILE;
    int wave = t >> 6, lane = t & 63;
    int q = lane >> 4, r = lane & 15;

    // this wave's mtile edge for lane r
    int eg = e0 + wave * 16 + r;
    int ec = eg < E ? eg : E - 1;
    int ii = pairs[((size_t)b * E + ec) * 2 + 0];
    int jj = pairs[((size_t)b * E + ec) * 2 + 1];
    const float* pI = featT + ((size_t)b * NN + ii) * CC + q * 8;
    const float* pJ = featT + ((size_t)b * NN + jj) * CC + q * 8;

    v4f acc[4];
    #pragma unroll
    for (int nt = 0; nt < 4; ++nt) acc[nt] = (v4f)0.f;

    float fi[3][8], fj[3][8];
    auto LOAD = [&](int ks, int buf) {
        const float4* a = (const float4*)(pI + ks * 32);
        const float4* c = (const float4*)(pJ + ks * 32);
        *(float4*)&fi[buf][0] = a[0];
        *(float4*)&fi[buf][4] = a[1];
        *(float4*)&fj[buf][0] = c[0];
        *(float4*)&fj[buf][4] = c[1];
    };

    LOAD(0, 0);
    LOAD(1, 1);
    __syncthreads();   // Wsh ready

    const bfrag* WH = (const bfrag*)Wsh;
    const bfrag* WL = (const bfrag*)(Wsh + 20480);   // byte offset 40960

    #pragma unroll
    for (int ks = 0; ks < 10; ++ks) {
        int cur = ks % 3;
        if (ks + 2 < 10) LOAD(ks + 2, (ks + 2) % 3);

        bfrag ah, al;
        #pragma unroll
        for (int kk = 0; kk < 8; ++kk) {
            float d = fabsf(fi[cur][kk] - fj[cur][kk]);
            __bf16 h = (__bf16)d;
            ah[kk] = h;
            al[kk] = (__bf16)(d - (float)h);
        }

        #pragma unroll
        for (int nt = 0; nt < 4; ++nt) {
            bfrag bh = WH[((ks * 4 + nt) << 6) + lane];   // ds_read_b128
            bfrag bl = WL[((ks * 4 + nt) << 6) + lane];
            acc[nt] = __builtin_amdgcn_mfma_f32_16x16x32_bf16(ah, bh, acc[nt], 0, 0, 0);
            acc[nt] = __builtin_amdgcn_mfma_f32_16x16x32_bf16(ah, bl, acc[nt], 0, 0, 0);
            acc[nt] = __builtin_amdgcn_mfma_f32_16x16x32_bf16(al, bh, acc[nt], 0, 0, 0);
        }
    }

    // epilogue: bias + store f32 h[b][e][64]; BN partials in registers
    float b1v[4];
    #pragma unroll
    for (int nt = 0; nt < 4; ++nt) b1v[nt] = b1[nt * 16 + r];

    float ps[4], ps2[4];
    #pragma unroll
    for (int nt = 0; nt < 4; ++nt) { ps[nt] = 0.f; ps2[nt] = 0.f; }

    #pragma unroll
    for (int reg = 0; reg < 4; ++reg) {
        int e = e0 + wave * 16 + q * 4 + reg;
        if (e < E) {
            float* hp = hstore + ((size_t)b * E + e) * PH + r;
            #pragma unroll
            for (int nt = 0; nt < 4; ++nt) {
                float v = acc[nt][reg] + b1v[nt];
                hp[nt * 16] = v;
                ps[nt] += v;
                ps2[nt] = fmaf(v, v, ps2[nt]);
            }
        }
    }

    // reuse Wsh for BN stats now that all waves are done with B-fragments
    __syncthreads();
    if (t < PH) { sS[t] = 0.f; sS2[t] = 0.f; }
    __syncthreads();
    #pragma unroll
    for (int nt = 0; nt < 4; ++nt) {
        atomicAdd(&sS[nt * 16 + r],  ps[nt]);
        atomicAdd(&sS2[nt * 16 + r], ps2[nt]);
    }
    __syncthreads();
    if (t < PH) {
        atomicAdd(&Ssum[b * PH + t],  sS[t]);
        atomicAdd(&S2sum[b * PH + t], sS2[t]);
    }
}

// -- stage 3: BN-final (in-block) + edge value + ELL scatter --------------
__global__ __launch_bounds__(256) void k_edge_val(
    const float* __restrict__ hstore, const float* __restrict__ Ssum,
    const float* __restrict__ S2sum, const float* __restrict__ gamma,
    const float* __restrict__ beta, const float* __restrict__ w2,
    const float* __restrict__ b2, const int* __restrict__ pairs,
    int* __restrict__ cnt, int* __restrict__ ecol, float* __restrict__ eval_,
    int E)
{
    __shared__ float ca[PH], cb[PH];
    int b = blockIdx.x % BB;
    int e = (blockIdx.x / BB) * 256 + threadIdx.x;
    if (threadIdx.x < PH) {
        int l = threadIdx.x;
        float mu = Ssum[b * PH + l] / E;
        float var = S2sum[b * PH + l] / E - mu * mu;
        float A = rsqrtf(var + 1e-5f) * gamma[l];
        ca[l] = A;
        cb[l] = beta[l] - mu * A;
    }
    __syncthreads();
    if (e >= E) return;
    const float4* hp = (const float4*)(hstore + ((size_t)b * E + e) * PH);
    float acc = 0.f;
    #pragma unroll
    for (int l4 = 0; l4 < 16; ++l4) {
        float4 v = hp[l4];
        float vv[4] = {v.x, v.y, v.z, v.w};
        #pragma unroll
        for (int c = 0; c < 4; ++c) {
            int l = l4 * 4 + c;
            float x = fmaf(vv[c], ca[l], cb[l]);
            x = x > 0.f ? x : 0.f;
            acc = fmaf(x, w2[l], acc);
        }
    }
    float edge = 1.f / (1.f + __expf(-(acc + b2[0])));
    const int* cp = pairs + ((size_t)b * E + e) * 2;
    int i = cp[0], j = cp[1];
    int row = b * NN + i;
    int slot = atomicAdd(&cnt[row], 1);
    if (slot < ELLW) {
        ecol[row * ELLW + slot]  = j;
        eval_[row * ELLW + slot] = edge;
    }
}

// ------ stage 4: g1 = featT @ gc1_w  (split-bf16 MFMA)
//   16 nodes/block, wave w owns ntiles {2w,2w+1} -> 1024 blocks, light waves.
__global__ __launch_bounds__(256) void k_gc1(
    const float* __restrict__ featT, const __bf16* __restrict__ gwhi,
    const __bf16* __restrict__ gwlo, float* __restrict__ g1)
{
    int b = blockIdx.x % BB;
    int m0 = b * NN + (blockIdx.x / BB) * 16;
    int t = threadIdx.x, wave = t >> 6, lane = t & 63;
    int q = lane >> 4, r = lane & 15;
    int nt0 = wave * 2;
    const float* fp = featT + (size_t)(m0 + r) * CC + q * 8;
    const bfrag* wh = (const bfrag*)gwhi;
    const bfrag* wl = (const bfrag*)gwlo;

    v4f acc[2];
    acc[0] = (v4f)0.f; acc[1] = (v4f)0.f;

    float fa[2][8];
    auto LOADA = [&](int ks, int buf) {
        const float4* p = (const float4*)(fp + ks * 32);
        *(float4*)&fa[buf][0] = p[0];
        *(float4*)&fa[buf][4] = p[1];
    };

    LOADA(0, 0);
    #pragma unroll
    for (int ks = 0; ks < 10; ++ks) {
        int cur = ks & 1;
        if (ks < 9) LOADA(ks + 1, cur ^ 1);
        bfrag ah, al;
        #pragma unroll
        for (int kk = 0; kk < 8; ++kk) {
            float d = fa[cur][kk];
            __bf16 h = (__bf16)d;
            ah[kk] = h;
            al[kk] = (__bf16)(d - (float)h);
        }
        #pragma unroll
        for (int dnt = 0; dnt < 2; ++dnt) {
            int nt = nt0 + dnt;
            bfrag bh = wh[((ks * 8 + nt) << 6) + lane];
            bfrag bl = wl[((ks * 8 + nt) << 6) + lane];
            acc[dnt] = __builtin_amdgcn_mfma_f32_16x16x32_bf16(ah, bh, acc[dnt], 0, 0, 0);
            acc[dnt] = __builtin_amdgcn_mfma_f32_16x16x32_bf16(ah, bl, acc[dnt], 0, 0, 0);
            acc[dnt] = __builtin_amdgcn_mfma_f32_16x16x32_bf16(al, bh, acc[dnt], 0, 0, 0);
        }
    }
    #pragma unroll
    for (int dnt = 0; dnt < 2; ++dnt) {
        #pragma unroll
        for (int reg = 0; reg < 4; ++reg) {
            int m = m0 + q * 4 + reg;
            g1[(size_t)m * GH + (nt0 + dnt) * 16 + r] = acc[dnt][reg];
        }
    }
}

// ------- stage 5: h1 = leaky(adj @ g1); g2 = h1 @ gc2_w (1 node/block) ---
__global__ __launch_bounds__(128) void k_spmm1(
    const float* __restrict__ g1, const int* __restrict__ cnt,
    const int* __restrict__ ecol, const float* __restrict__ eval_,
    const float* __restrict__ w2g, float* __restrict__ g2)
{
    __shared__ float tmp[2];
    int tid = threadIdx.x;
    int b = blockIdx.x % BB;
    int node = b * NN + blockIdx.x / BB;
    float wv = w2g[tid];
    int c = cnt[node];
    const int* ec = ecol + (size_t)node * ELLW;
    const float* ev = eval_ + (size_t)node * ELLW;
    float acc = 0.f;
    int s = 0;
    for (; s + 4 <= c; s += 4) {
        int j0 = ec[s], j1 = ec[s + 1], j2 = ec[s + 2], j3 = ec[s + 3];
        float v0 = ev[s], v1 = ev[s + 1], v2 = ev[s + 2], v3 = ev[s + 3];
        float a0 = g1[((size_t)b * NN + j0) * GH + tid];
        float a1 = g1[((size_t)b * NN + j1) * GH + tid];
        float a2 = g1[((size_t)b * NN + j2) * GH + tid];
        float a3 = g1[((size_t)b * NN + j3) * GH + tid];
        acc = fmaf(v0, a0, acc); acc = fmaf(v1, a1, acc);
        acc = fmaf(v2, a2, acc); acc = fmaf(v3, a3, acc);
    }
    for (; s < c; ++s) {
        int j = ec[s];
        acc = fmaf(ev[s], g1[((size_t)b * NN + j) * GH + tid], acc);
    }
    float h1 = acc > 0.f ? acc : 0.2f * acc;
    float p = h1 * wv;
    #pragma unroll
    for (int off = 32; off >= 1; off >>= 1) p += __shfl_down(p, off, 64);
    if ((tid & 63) == 0) tmp[tid >> 6] = p;
    __syncthreads();
    if (tid == 0) g2[node] = tmp[0] + tmp[1];
}

// ------------- stage 6: out = sigmoid(adj @ g2) (1 wave/node, lane=slot) -
__global__ __launch_bounds__(64) void k_spmm2(
    const float* __restrict__ g2, const int* __restrict__ cnt,
    const int* __restrict__ ecol, const float* __restrict__ eval_,
    float* __restrict__ out)
{
    int b = blockIdx.x % BB;
    int node = b * NN + blockIdx.x / BB;
    int lane = threadIdx.x;
    int c = cnt[node];
    float p = 0.f;
    if (lane < c) {
        int j = ecol[(size_t)node * ELLW + lane];
        p = eval_[(size_t)node * ELLW + lane] * g2[b * NN + j];
    }
    #pragma unroll
    for (int off = 32; off >= 1; off >>= 1) p += __shfl_down(p, off, 64);
    if (lane == 0) out[node] = 1.f / (1.f + __expf(-p));
}

extern "C" void kernel_launch(void* const* d_in, const int* in_sizes, int n_in,
                              void* d_out, int out_size, void* d_ws, size_t ws_size,
                              hipStream_t stream)
{
    const float* search = (const float*)d_in[0];
    const float* xcorr  = (const float*)d_in[1];
    const int*   pairs  = (const int*)d_in[2];
    const float* w1     = (const float*)d_in[3];
    const float* b1     = (const float*)d_in[4];
    const float* gamma  = (const float*)d_in[5];
    const float* beta   = (const float*)d_in[6];
    const float* w2     = (const float*)d_in[7];
    const float* b2     = (const float*)d_in[8];
    const float* gc1w   = (const float*)d_in[9];
    const float* gc2w   = (const float*)d_in[10];
    float* out = (float*)d_out;

    int E = in_sizes[2] / (BB * 2);      // 10068
    int nb  = (E + 255) / 256;           // 40
    int nb2 = (E + MTILE - 1) / MTILE;   // 79

    char* ws = (char*)d_ws;
    size_t off = 0;
    auto alloc = [&](size_t bytes) {
        size_t o = off;
        off += (bytes + 255) & ~(size_t)255;
        return o;
    };
    __bf16* whi   = (__bf16*)(ws + alloc(10 * 4 * 64 * 8 * 2));   // 40960 B
    __bf16* wlo   = (__bf16*)(ws + alloc(10 * 4 * 64 * 8 * 2));   // contiguous after whi
    __bf16* gwhi  = (__bf16*)(ws + alloc(10 * 8 * 64 * 8 * 2));
    __bf16* gwlo  = (__bf16*)(ws + alloc(10 * 8 * 64 * 8 * 2));
    float* featT  = (float*)(ws + alloc((size_t)BB * NN * CC * 4));
    float* hstore = (float*)(ws + alloc((size_t)BB * E * PH * 4));
    float* Ssum   = (float*)(ws + alloc(BB * PH * 4));
    float* S2sum  = (float*)(ws + alloc(BB * PH * 4));
    int*   cnt    = (int*)(ws + alloc(BB * NN * 4));
    int*   ecol   = (int*)(ws + alloc((size_t)BB * NN * ELLW * 4));
    float* eval_  = (float*)(ws + alloc((size_t)BB * NN * ELLW * 4));
    float* g1     = (float*)(ws + alloc((size_t)BB * NN * GH * 4));
    float* g2     = (float*)(ws + alloc(BB * NN * 4));
    (void)ws_size; (void)n_in; (void)out_size;

    k_prep<<<dim3(160), dim3(256), 0, stream>>>(w1, gc1w, whi, wlo, gwhi, gwlo,
                                                cnt, Ssum, S2sum);
    k_transpose<<<dim3(BB * 320), dim3(256), 0, stream>>>(search, xcorr, featT);
    k_edge_gemm<<<dim3(BB * nb2), dim3(512), 0, stream>>>(featT, pairs,
                                                          (const uint4*)whi,
                                                          b1, hstore, Ssum, S2sum, E);
    k_edge_val<<<dim3(BB * nb), dim3(256), 0, stream>>>(hstore, Ssum, S2sum,
                                                        gamma, beta, w2, b2,
                                                        pairs, cnt, ecol, eval_, E);
    k_gc1<<<dim3(BB * (NN / 16)), dim3(256), 0, stream>>>(featT, gwhi, gwlo, g1);
    k_spmm1<<<dim3(BB * NN), dim3(128), 0, stream>>>(g1, cnt, ecol, eval_, gc2w, g2);
    k_spmm2<<<dim3(BB * NN), dim3(64), 0, stream>>>(g2, cnt, ecol, eval_, out);
}